// Round 2
// baseline (516.908 us; speedup 1.0000x reference)
//
#include <hip/hip_runtime.h>

#define OBS_DIM 64
#define ACT_DIM 12
#define IN_DIM  76
#define HID     256
#define BATCH   1024
#define CAP     100000
#define NKT     64
#define NCHUNK  ((CAP + NKT - 1) / NKT)      /* 1563 */
#define CGRP    16
#define CPG     ((NCHUNK + CGRP - 1) / CGRP) /* 98 */
#define LOG2E   1.4426950408889634f

typedef __attribute__((ext_vector_type(8)))  _Float16 f16x8;
typedef __attribute__((ext_vector_type(4)))  _Float16 f16x4;
typedef __attribute__((ext_vector_type(4)))  float    f32x4;
typedef __attribute__((ext_vector_type(16))) float    f32x16;

// ---------------- trunk: x@W + b, LayerNorm, tanh -> A (fp16) ----------------
__global__ __launch_bounds__(256) void np_trunk(const float* __restrict__ obs,
                                                const float* __restrict__ act,
                                                const float* __restrict__ W,
                                                const float* __restrict__ bias,
                                                const float* __restrict__ gamma,
                                                const float* __restrict__ beta,
                                                _Float16* __restrict__ A) {
    const int row = blockIdx.x;
    const int t = threadIdx.x;
    __shared__ float x[80];
    __shared__ float red[8];
    if (t < OBS_DIM) x[t] = obs[row * OBS_DIM + t];
    else if (t < IN_DIM) x[t] = act[row * ACT_DIM + (t - OBS_DIM)];
    __syncthreads();
    float h = bias[t];
#pragma unroll
    for (int k = 0; k < IN_DIM; ++k) h = fmaf(x[k], W[k * HID + t], h);
    float s1 = h, s2 = h * h;
#pragma unroll
    for (int m = 1; m < 64; m <<= 1) { s1 += __shfl_xor(s1, m, 64); s2 += __shfl_xor(s2, m, 64); }
    const int wave = t >> 6;
    if ((t & 63) == 0) { red[wave] = s1; red[4 + wave] = s2; }
    __syncthreads();
    const float S1 = red[0] + red[1] + red[2] + red[3];
    const float S2 = red[4] + red[5] + red[6] + red[7];
    const float mu = S1 * (1.0f / 256.0f);
    const float var = S2 * (1.0f / 256.0f) - mu * mu;
    const float rs = rsqrtf(var + 1e-5f);
    const float g = (h - mu) * rs * gamma[t] + beta[t];
    const float e = exp2f(g * (2.0f * LOG2E));
    const float ph = 1.0f - 2.0f / (e + 1.0f);
    A[row * HID + t] = (_Float16)ph;
}

// ------------- key-stationary fused GEMM + per-64-key-tile softmax -------------
// Operand-swapped: keys = A (M), phi = B (N). mfma_f32_32x32x16_f16.
// D layout: batch-row = lane&31 (one row/lane), key = (reg&3)+8*(reg>>2)+4*(lane>>5)
// -> softmax over keys is in-register + ONE xor-32 shuffle stage.
__global__ __launch_bounds__(256, 4) void np_gemm(const float* __restrict__ keys,
                                                  const float* __restrict__ vals,
                                                  const _Float16* __restrict__ A,
                                                  float* __restrict__ pm,
                                                  float* __restrict__ pl,
                                                  float* __restrict__ pa) {
    const int chunk = blockIdx.x;
    const int kb = chunk * NKT;
    const int t = threadIdx.x;
    const int lane = t & 63;
    const int wave = t >> 6;
    const int g = lane >> 5;      // k-half group
    const int n32 = lane & 31;    // batch row within 32-tile

    __shared__ __align__(16) _Float16 Bt[16][2][64][8]; // [kstep16][g][key][8 halfs] = 32 KB
    __shared__ float nred[256];
    __shared__ float n2c[64];     // |k|^2 / 2  (1e30 for pad keys)
    __shared__ float vv[64];

    // ---- stage keys fp32 -> fp16 LDS (32x32x16 A-frag layout) + fp32 sq-sums ----
    {
        const int keyl = t >> 2;
        const int key = kb + keyl;
        const int k0 = (t & 3) * 64;
        const bool ok = key < CAP;
        const float* src = keys + (size_t)key * HID + k0;
        float sq = 0.f;
#pragma unroll
        for (int i = 0; i < 16; ++i) {
            float4 f = make_float4(0.f, 0.f, 0.f, 0.f);
            if (ok) f = ((const float4*)src)[i];
            sq = fmaf(f.x, f.x, sq); sq = fmaf(f.y, f.y, sq);
            sq = fmaf(f.z, f.z, sq); sq = fmaf(f.w, f.w, sq);
            const int k = k0 + i * 4;
            f16x4 hv = {(_Float16)f.x, (_Float16)f.y, (_Float16)f.z, (_Float16)f.w};
            *(f16x4*)(&Bt[k >> 4][(k >> 3) & 1][keyl][k & 7]) = hv;
        }
        nred[t] = sq;
        if (t < NKT) {
            float v = 0.f;
            if (kb + t < CAP) v = vals[kb + t];
            vv[t] = v;
        }
    }
    __syncthreads();
    if (t < NKT) {
        const float n = nred[4 * t] + nred[4 * t + 1] + nred[4 * t + 2] + nred[4 * t + 3];
        n2c[t] = (kb + t < CAP) ? n * 0.5f : 1e30f;
    }
    __syncthreads();

    const float C1 = 2.0f * LOG2E;
    union U { f32x16 v; f32x4 q[4]; float f[16]; };

#pragma unroll 1
    for (int rg = 0; rg < 8; ++rg) {
        const int rowbase = rg * 128 + wave * 32;
        const _Float16* ap = A + (size_t)(rowbase + n32) * HID + g * 8;

        // acc init = -|k|^2/2 per owned key -> logit = C1 * acc_final
        U acc0, acc1;
#pragma unroll
        for (int rq = 0; rq < 4; ++rq) {
            f32x4 a = *(const f32x4*)&n2c[rq * 8 + g * 4];
            f32x4 b = *(const f32x4*)&n2c[32 + rq * 8 + g * 4];
            acc0.q[rq] = -a;
            acc1.q[rq] = -b;
        }

#pragma unroll
        for (int ks = 0; ks < 16; ++ks) {
            f16x8 bf  = *(const f16x8*)(ap + ks * 16);
            f16x8 kf0 = *(const f16x8*)(&Bt[ks][g][n32][0]);
            f16x8 kf1 = *(const f16x8*)(&Bt[ks][g][32 + n32][0]);
            acc0.v = __builtin_amdgcn_mfma_f32_32x32x16_f16(kf0, bf, acc0.v, 0, 0, 0);
            acc1.v = __builtin_amdgcn_mfma_f32_32x32x16_f16(kf1, bf, acc1.v, 0, 0, 0);
        }

        // ---- in-register softmax partials over the 64-key tile ----
        float m = -3e38f;
#pragma unroll
        for (int r = 0; r < 16; ++r) {
            acc0.f[r] *= C1;
            acc1.f[r] *= C1;
            m = fmaxf(m, fmaxf(acc0.f[r], acc1.f[r]));
        }
        m = fmaxf(m, __shfl_xor(m, 32, 64));   // single cross-lane stage

        float lsum = 0.f, asum = 0.f;
#pragma unroll
        for (int rq = 0; rq < 4; ++rq) {
            f32x4 v0 = *(const f32x4*)&vv[rq * 8 + g * 4];
            f32x4 v1 = *(const f32x4*)&vv[32 + rq * 8 + g * 4];
#pragma unroll
            for (int j = 0; j < 4; ++j) {
                const float w0 = exp2f(acc0.f[rq * 4 + j] - m);
                const float w1 = exp2f(acc1.f[rq * 4 + j] - m);
                lsum += w0 + w1;
                asum = fmaf(w0, v0[j], fmaf(w1, v1[j], asum));
            }
        }
        lsum += __shfl_xor(lsum, 32, 64);       // single cross-lane stage
        asum += __shfl_xor(asum, 32, 64);

        if (lane < 32) {
            const int row = rowbase + n32;
            const size_t idx = (size_t)chunk * BATCH + row;
            pm[idx] = m; pl[idx] = lsum; pa[idx] = asum;
        }
    }
}

// ------------- merge stage 1: 16 chunk-groups x 16 row-blocks -------------
__global__ __launch_bounds__(256) void np_merge1(const float* __restrict__ pm,
                                                 const float* __restrict__ pl,
                                                 const float* __restrict__ pa,
                                                 float* __restrict__ pm2,
                                                 float* __restrict__ pl2,
                                                 float* __restrict__ pa2) {
    const int rb = blockIdx.x & 15;
    const int cgB = blockIdx.x >> 4;
    const int t = threadIdx.x;
    const int row = rb * 64 + (t & 63);
    const int cg = t >> 6;
    const int cend = min((cgB + 1) * CPG, NCHUNK);
    float M = -3e38f, L = 0.f, Acc = 0.f;
    for (int c = cgB * CPG + cg; c < cend; c += 4) {
        const size_t idx = (size_t)c * BATCH + row;
        const float m = pm[idx], l = pl[idx], a = pa[idx];
        const float Mn = fmaxf(M, m);
        const float s0 = exp2f(M - Mn);
        const float s1 = exp2f(m - Mn);
        L = fmaf(L, s0, l * s1);
        Acc = fmaf(Acc, s0, a * s1);
        M = Mn;
    }
    __shared__ float sm[256], sl[256], sa[256];
    sm[t] = M; sl[t] = L; sa[t] = Acc;
    __syncthreads();
    if (t < 64) {
        const float M0 = sm[t], M1 = sm[t + 64], M2 = sm[t + 128], M3 = sm[t + 192];
        const float Mf = fmaxf(fmaxf(M0, M1), fmaxf(M2, M3));
        const float e0 = exp2f(M0 - Mf), e1 = exp2f(M1 - Mf), e2 = exp2f(M2 - Mf), e3 = exp2f(M3 - Mf);
        const float Lf = sl[t] * e0 + sl[t + 64] * e1 + sl[t + 128] * e2 + sl[t + 192] * e3;
        const float Af = sa[t] * e0 + sa[t + 64] * e1 + sa[t + 128] * e2 + sa[t + 192] * e3;
        const size_t o = (size_t)cgB * BATCH + rb * 64 + t;
        pm2[o] = Mf; pl2[o] = Lf; pa2[o] = Af;
    }
}

// ------------- merge stage 2: final 16-way merge, write q1==q2 -------------
__global__ __launch_bounds__(256) void np_merge2(const float* __restrict__ pm2,
                                                 const float* __restrict__ pl2,
                                                 const float* __restrict__ pa2,
                                                 float* __restrict__ out) {
    const int row = blockIdx.x * 256 + threadIdx.x;
    float M = -3e38f, L = 0.f, Acc = 0.f;
#pragma unroll 1
    for (int g = 0; g < CGRP; ++g) {
        const size_t idx = (size_t)g * BATCH + row;
        const float m = pm2[idx], l = pl2[idx], a = pa2[idx];
        const float Mn = fmaxf(M, m);
        const float s0 = exp2f(M - Mn);
        const float s1 = exp2f(m - Mn);
        L = fmaf(L, s0, l * s1);
        Acc = fmaf(Acc, s0, a * s1);
        M = Mn;
    }
    const float qv = Acc / L;
    out[row] = qv;
    out[BATCH + row] = qv;
}

extern "C" void kernel_launch(void* const* d_in, const int* in_sizes, int n_in,
                              void* d_out, int out_size, void* d_ws, size_t ws_size,
                              hipStream_t stream) {
    const float* obs   = (const float*)d_in[0];
    const float* act   = (const float*)d_in[1];
    const float* W     = (const float*)d_in[2];
    const float* bias  = (const float*)d_in[3];
    const float* gamma = (const float*)d_in[4];
    const float* beta  = (const float*)d_in[5];
    const float* keys  = (const float*)d_in[6];
    const float* vals  = (const float*)d_in[7];
    float* out = (float*)d_out;

    char* w = (char*)d_ws;
    _Float16* A = (_Float16*)w;                       // 512 KB
    float* pm = (float*)(w + (1 << 19));
    float* pl = pm + (size_t)NCHUNK * BATCH;          // 3 x 6.25 MB
    float* pa = pl + (size_t)NCHUNK * BATCH;
    float* pm2 = pa + (size_t)NCHUNK * BATCH;         // 3 x 64 KB
    float* pl2 = pm2 + (size_t)CGRP * BATCH;
    float* pa2 = pl2 + (size_t)CGRP * BATCH;

    np_trunk<<<BATCH, 256, 0, stream>>>(obs, act, W, bias, gamma, beta, A);
    np_gemm<<<NCHUNK, 256, 0, stream>>>(keys, vals, A, pm, pl, pa);
    np_merge1<<<CGRP * 16, 256, 0, stream>>>(pm, pl, pa, pm2, pl2, pa2);
    np_merge2<<<BATCH / 256, 256, 0, stream>>>(pm2, pl2, pa2, out);
}

// Round 3
// 460.719 us; speedup vs baseline: 1.1220x; 1.1220x over previous
//
#include <hip/hip_runtime.h>

#define OBS_DIM 64
#define ACT_DIM 12
#define IN_DIM  76
#define HID     256
#define BATCH   1024
#define CAP     100000
#define NKT     64
#define NCHUNK  ((CAP + NKT - 1) / NKT)      /* 1563 */
#define CGRP    16
#define CPG     ((NCHUNK + CGRP - 1) / CGRP) /* 98 */
#define LOG2E   1.4426950408889634f

typedef __attribute__((ext_vector_type(8)))  _Float16 f16x8;
typedef __attribute__((ext_vector_type(4)))  _Float16 f16x4;
typedef __attribute__((ext_vector_type(4)))  float    f32x4;
typedef __attribute__((ext_vector_type(16))) float    f32x16;

// ---------------- trunk: x@W + b, LayerNorm, tanh -> A (fp16) ----------------
__global__ __launch_bounds__(256) void np_trunk(const float* __restrict__ obs,
                                                const float* __restrict__ act,
                                                const float* __restrict__ W,
                                                const float* __restrict__ bias,
                                                const float* __restrict__ gamma,
                                                const float* __restrict__ beta,
                                                _Float16* __restrict__ A) {
    const int row = blockIdx.x;
    const int t = threadIdx.x;
    __shared__ float x[80];
    __shared__ float red[8];
    if (t < OBS_DIM) x[t] = obs[row * OBS_DIM + t];
    else if (t < IN_DIM) x[t] = act[row * ACT_DIM + (t - OBS_DIM)];
    __syncthreads();
    float h = bias[t];
#pragma unroll
    for (int k = 0; k < IN_DIM; ++k) h = fmaf(x[k], W[k * HID + t], h);
    float s1 = h, s2 = h * h;
#pragma unroll
    for (int m = 1; m < 64; m <<= 1) { s1 += __shfl_xor(s1, m, 64); s2 += __shfl_xor(s2, m, 64); }
    const int wave = t >> 6;
    if ((t & 63) == 0) { red[wave] = s1; red[4 + wave] = s2; }
    __syncthreads();
    const float S1 = red[0] + red[1] + red[2] + red[3];
    const float S2 = red[4] + red[5] + red[6] + red[7];
    const float mu = S1 * (1.0f / 256.0f);
    const float var = S2 * (1.0f / 256.0f) - mu * mu;
    const float rs = rsqrtf(var + 1e-5f);
    const float g = (h - mu) * rs * gamma[t] + beta[t];
    const float e = exp2f(g * (2.0f * LOG2E));
    const float ph = 1.0f - 2.0f / (e + 1.0f);
    A[row * HID + t] = (_Float16)ph;
}

// ------------- key-stationary fused GEMM + per-64-key-tile softmax -------------
// Operand-swapped: keys = A (M), phi = B (N). mfma_f32_32x32x16_f16.
// D layout: batch-row = lane&31 (one row/lane), key = (reg&3)+8*(reg>>2)+4*(lane>>5)
// -> softmax over keys is in-register + ONE xor-32 shuffle stage.
// launch_bounds(256,3): VGPR budget ~168 -> NO SPILL (256,4 spilled accs to
// scratch: FETCH 825 MB / WRITE 206 MB in round 2). 3 blocks/CU, 12 waves/CU.
__global__ __launch_bounds__(256, 3) void np_gemm(const float* __restrict__ keys,
                                                  const float* __restrict__ vals,
                                                  const _Float16* __restrict__ A,
                                                  float* __restrict__ pm,
                                                  float* __restrict__ pl,
                                                  float* __restrict__ pa) {
    const int chunk = blockIdx.x;
    const int kb = chunk * NKT;
    const int t = threadIdx.x;
    const int lane = t & 63;
    const int wave = t >> 6;
    const int g = lane >> 5;      // k-half group
    const int n32 = lane & 31;    // batch row within 32-tile

    __shared__ __align__(16) _Float16 Bt[16][2][64][8]; // [kstep16][g][key][8 halfs] = 32 KB
    __shared__ float nred[256];
    __shared__ float n2c[64];     // |k|^2 / 2  (1e30 for pad keys)
    __shared__ float vv[64];

    // ---- stage keys fp32 -> fp16 LDS (32x32x16 A-frag layout) + fp32 sq-sums ----
    {
        const int keyl = t >> 2;
        const int key = kb + keyl;
        const int k0 = (t & 3) * 64;
        const bool ok = key < CAP;
        const float* src = keys + (size_t)key * HID + k0;
        float sq = 0.f;
#pragma unroll
        for (int i = 0; i < 16; ++i) {
            float4 f = make_float4(0.f, 0.f, 0.f, 0.f);
            if (ok) f = ((const float4*)src)[i];
            sq = fmaf(f.x, f.x, sq); sq = fmaf(f.y, f.y, sq);
            sq = fmaf(f.z, f.z, sq); sq = fmaf(f.w, f.w, sq);
            const int k = k0 + i * 4;
            f16x4 hv = {(_Float16)f.x, (_Float16)f.y, (_Float16)f.z, (_Float16)f.w};
            *(f16x4*)(&Bt[k >> 4][(k >> 3) & 1][keyl][k & 7]) = hv;
        }
        nred[t] = sq;
        if (t < NKT) {
            float v = 0.f;
            if (kb + t < CAP) v = vals[kb + t];
            vv[t] = v;
        }
    }
    __syncthreads();
    if (t < NKT) {
        const float n = nred[4 * t] + nred[4 * t + 1] + nred[4 * t + 2] + nred[4 * t + 3];
        n2c[t] = (kb + t < CAP) ? n * 0.5f : 1e30f;
    }
    __syncthreads();

    const float C1 = 2.0f * LOG2E;
    union U { f32x16 v; f32x4 q[4]; float f[16]; };

#pragma unroll 1
    for (int rg = 0; rg < 8; ++rg) {
        const int rowbase = rg * 128 + wave * 32;
        const _Float16* ap = A + (size_t)(rowbase + n32) * HID + g * 8;

        // acc init = -|k|^2/2 per owned key -> logit = C1 * acc_final
        U acc0, acc1;
#pragma unroll
        for (int rq = 0; rq < 4; ++rq) {
            f32x4 a = *(const f32x4*)&n2c[rq * 8 + g * 4];
            f32x4 b = *(const f32x4*)&n2c[32 + rq * 8 + g * 4];
            acc0.q[rq] = -a;
            acc1.q[rq] = -b;
        }

#pragma unroll
        for (int ks = 0; ks < 16; ++ks) {
            f16x8 bf  = *(const f16x8*)(ap + ks * 16);
            f16x8 kf0 = *(const f16x8*)(&Bt[ks][g][n32][0]);
            f16x8 kf1 = *(const f16x8*)(&Bt[ks][g][32 + n32][0]);
            acc0.v = __builtin_amdgcn_mfma_f32_32x32x16_f16(kf0, bf, acc0.v, 0, 0, 0);
            acc1.v = __builtin_amdgcn_mfma_f32_32x32x16_f16(kf1, bf, acc1.v, 0, 0, 0);
        }

        // ---- in-register softmax partials over the 64-key tile ----
        float m = -3e38f;
#pragma unroll
        for (int r = 0; r < 16; ++r)
            m = fmaxf(m, fmaxf(acc0.f[r], acc1.f[r]));
        m = fmaxf(m, __shfl_xor(m, 32, 64));   // single cross-lane stage

        float lsum = 0.f, asum = 0.f;
#pragma unroll
        for (int r = 0; r < 16; ++r) {
            const int key = (r & 3) + 8 * (r >> 2) + 4 * g;
            const float w0 = exp2f(fmaf(acc0.f[r], C1, -m * C1) * (1.0f / C1) * C1); // folded below
            (void)w0;
        }
        // (clean version below — single pass, minimal live temps)
        lsum = 0.f; asum = 0.f;
#pragma unroll
        for (int r = 0; r < 16; ++r) {
            const int key0 = (r & 3) + 8 * (r >> 2) + 4 * g;
            const float w0 = exp2f(acc0.f[r] * C1 - m);
            const float w1 = exp2f(acc1.f[r] * C1 - m);
            lsum += w0 + w1;
            asum = fmaf(w0, vv[key0], fmaf(w1, vv[32 + key0], asum));
        }
        lsum += __shfl_xor(lsum, 32, 64);       // single cross-lane stage
        asum += __shfl_xor(asum, 32, 64);

        if (lane < 32) {
            const int row = rowbase + n32;
            const size_t idx = (size_t)chunk * BATCH + row;
            pm[idx] = m; pl[idx] = lsum; pa[idx] = asum;
        }
    }
}

// ------------- merge stage 1: 16 chunk-groups x 16 row-blocks -------------
__global__ __launch_bounds__(256) void np_merge1(const float* __restrict__ pm,
                                                 const float* __restrict__ pl,
                                                 const float* __restrict__ pa,
                                                 float* __restrict__ pm2,
                                                 float* __restrict__ pl2,
                                                 float* __restrict__ pa2) {
    const int rb = blockIdx.x & 15;
    const int cgB = blockIdx.x >> 4;
    const int t = threadIdx.x;
    const int row = rb * 64 + (t & 63);
    const int cg = t >> 6;
    const int cend = min((cgB + 1) * CPG, NCHUNK);
    float M = -3e38f, L = 0.f, Acc = 0.f;
    for (int c = cgB * CPG + cg; c < cend; c += 4) {
        const size_t idx = (size_t)c * BATCH + row;
        const float m = pm[idx], l = pl[idx], a = pa[idx];
        const float Mn = fmaxf(M, m);
        const float s0 = exp2f(M - Mn);
        const float s1 = exp2f(m - Mn);
        L = fmaf(L, s0, l * s1);
        Acc = fmaf(Acc, s0, a * s1);
        M = Mn;
    }
    __shared__ float sm[256], sl[256], sa[256];
    sm[t] = M; sl[t] = L; sa[t] = Acc;
    __syncthreads();
    if (t < 64) {
        const float M0 = sm[t], M1 = sm[t + 64], M2 = sm[t + 128], M3 = sm[t + 192];
        const float Mf = fmaxf(fmaxf(M0, M1), fmaxf(M2, M3));
        const float e0 = exp2f(M0 - Mf), e1 = exp2f(M1 - Mf), e2 = exp2f(M2 - Mf), e3 = exp2f(M3 - Mf);
        const float Lf = sl[t] * e0 + sl[t + 64] * e1 + sl[t + 128] * e2 + sl[t + 192] * e3;
        const float Af = sa[t] * e0 + sa[t + 64] * e1 + sa[t + 128] * e2 + sa[t + 192] * e3;
        const size_t o = (size_t)cgB * BATCH + rb * 64 + t;
        pm2[o] = Mf; pl2[o] = Lf; pa2[o] = Af;
    }
}

// ------------- merge stage 2: final 16-way merge, write q1==q2 -------------
__global__ __launch_bounds__(256) void np_merge2(const float* __restrict__ pm2,
                                                 const float* __restrict__ pl2,
                                                 const float* __restrict__ pa2,
                                                 float* __restrict__ out) {
    const int row = blockIdx.x * 256 + threadIdx.x;
    float M = -3e38f, L = 0.f, Acc = 0.f;
#pragma unroll 1
    for (int g = 0; g < CGRP; ++g) {
        const size_t idx = (size_t)g * BATCH + row;
        const float m = pm2[idx], l = pl2[idx], a = pa2[idx];
        const float Mn = fmaxf(M, m);
        const float s0 = exp2f(M - Mn);
        const float s1 = exp2f(m - Mn);
        L = fmaf(L, s0, l * s1);
        Acc = fmaf(Acc, s0, a * s1);
        M = Mn;
    }
    const float qv = Acc / L;
    out[row] = qv;
    out[BATCH + row] = qv;
}

extern "C" void kernel_launch(void* const* d_in, const int* in_sizes, int n_in,
                              void* d_out, int out_size, void* d_ws, size_t ws_size,
                              hipStream_t stream) {
    const float* obs   = (const float*)d_in[0];
    const float* act   = (const float*)d_in[1];
    const float* W     = (const float*)d_in[2];
    const float* bias  = (const float*)d_in[3];
    const float* gamma = (const float*)d_in[4];
    const float* beta  = (const float*)d_in[5];
    const float* keys  = (const float*)d_in[6];
    const float* vals  = (const float*)d_in[7];
    float* out = (float*)d_out;

    char* w = (char*)d_ws;
    _Float16* A = (_Float16*)w;                       // 512 KB
    float* pm = (float*)(w + (1 << 19));
    float* pl = pm + (size_t)NCHUNK * BATCH;          // 3 x 6.25 MB
    float* pa = pl + (size_t)NCHUNK * BATCH;
    float* pm2 = pa + (size_t)NCHUNK * BATCH;         // 3 x 64 KB
    float* pl2 = pm2 + (size_t)CGRP * BATCH;
    float* pa2 = pl2 + (size_t)CGRP * BATCH;

    np_trunk<<<BATCH, 256, 0, stream>>>(obs, act, W, bias, gamma, beta, A);
    np_gemm<<<NCHUNK, 256, 0, stream>>>(keys, vals, A, pm, pl, pa);
    np_merge1<<<CGRP * 16, 256, 0, stream>>>(pm, pl, pa, pm2, pl2, pa2);
    np_merge2<<<BATCH / 256, 256, 0, stream>>>(pm2, pl2, pa2, out);
}

// Round 4
// 349.281 us; speedup vs baseline: 1.4799x; 1.3190x over previous
//
#include <hip/hip_runtime.h>

#define OBS_DIM 64
#define ACT_DIM 12
#define IN_DIM  76
#define HID     256
#define BATCH   1024
#define CAP     100000
#define NKT     64
#define NCHUNK  ((CAP + NKT - 1) / NKT)      /* 1563 */
#define CGRP    16
#define CPG     ((NCHUNK + CGRP - 1) / CGRP) /* 98 */
#define LOG2E   1.4426950408889634f

typedef __attribute__((ext_vector_type(8)))  _Float16 f16x8;
typedef __attribute__((ext_vector_type(4)))  _Float16 f16x4;
typedef __attribute__((ext_vector_type(4)))  float    f32x4;
typedef __attribute__((ext_vector_type(16))) float    f32x16;

// ---------------- trunk: x@W + b, LayerNorm, tanh -> A (fp16) ----------------
__global__ __launch_bounds__(256) void np_trunk(const float* __restrict__ obs,
                                                const float* __restrict__ act,
                                                const float* __restrict__ W,
                                                const float* __restrict__ bias,
                                                const float* __restrict__ gamma,
                                                const float* __restrict__ beta,
                                                _Float16* __restrict__ A) {
    const int row = blockIdx.x;
    const int t = threadIdx.x;
    __shared__ float x[80];
    __shared__ float red[8];
    if (t < OBS_DIM) x[t] = obs[row * OBS_DIM + t];
    else if (t < IN_DIM) x[t] = act[row * ACT_DIM + (t - OBS_DIM)];
    __syncthreads();
    float h = bias[t];
#pragma unroll
    for (int k = 0; k < IN_DIM; ++k) h = fmaf(x[k], W[k * HID + t], h);
    float s1 = h, s2 = h * h;
#pragma unroll
    for (int m = 1; m < 64; m <<= 1) { s1 += __shfl_xor(s1, m, 64); s2 += __shfl_xor(s2, m, 64); }
    const int wave = t >> 6;
    if ((t & 63) == 0) { red[wave] = s1; red[4 + wave] = s2; }
    __syncthreads();
    const float S1 = red[0] + red[1] + red[2] + red[3];
    const float S2 = red[4] + red[5] + red[6] + red[7];
    const float mu = S1 * (1.0f / 256.0f);
    const float var = S2 * (1.0f / 256.0f) - mu * mu;
    const float rs = rsqrtf(var + 1e-5f);
    const float g = (h - mu) * rs * gamma[t] + beta[t];
    const float e = exp2f(g * (2.0f * LOG2E));
    const float ph = 1.0f - 2.0f / (e + 1.0f);
    A[row * HID + t] = (_Float16)ph;
}

// ------------- key-stationary fused GEMM + per-64-key-tile softmax -------------
// Operand-swapped: keys = A (M), phi = B (N). mfma_f32_32x32x16_f16.
// D layout: batch-row = lane&31 (one row/lane), key = (reg&3)+8*(reg>>2)+4*(lane>>5)
// -> softmax over keys is in-register + ONE xor-32 shuffle stage.
// NO min-waves in launch_bounds: every forced cap ((256,4) r2, (256,3) r3)
// spilled the accumulators to scratch (FETCH/WRITE inflation). True demand
// ~116 regs; let the allocator have them, HW settles at ~3 waves/SIMD.
__global__ __launch_bounds__(256) void np_gemm(const float* __restrict__ keys,
                                               const float* __restrict__ vals,
                                               const _Float16* __restrict__ A,
                                               float* __restrict__ pm,
                                               float* __restrict__ pl,
                                               float* __restrict__ pa) {
    const int chunk = blockIdx.x;
    const int kb = chunk * NKT;
    const int t = threadIdx.x;
    const int lane = t & 63;
    const int wave = t >> 6;
    const int g = lane >> 5;      // k-half group
    const int n32 = lane & 31;    // batch row within 32-tile

    __shared__ __align__(16) _Float16 Bt[16][2][64][8]; // [kstep16][g][key][8 halfs] = 32 KB
    __shared__ float nred[256];
    __shared__ float n2c[64];     // |k|^2 / 2  (1e30 for pad keys)
    __shared__ float vv[64];

    // ---- stage keys fp32 -> fp16 LDS (32x32x16 A-frag layout) + fp32 sq-sums ----
    {
        const int keyl = t >> 2;
        const int key = kb + keyl;
        const int k0 = (t & 3) * 64;
        const bool ok = key < CAP;
        const float* src = keys + (size_t)key * HID + k0;
        float sq = 0.f;
#pragma unroll
        for (int i = 0; i < 16; ++i) {
            float4 f = make_float4(0.f, 0.f, 0.f, 0.f);
            if (ok) f = ((const float4*)src)[i];
            sq = fmaf(f.x, f.x, sq); sq = fmaf(f.y, f.y, sq);
            sq = fmaf(f.z, f.z, sq); sq = fmaf(f.w, f.w, sq);
            const int k = k0 + i * 4;
            f16x4 hv = {(_Float16)f.x, (_Float16)f.y, (_Float16)f.z, (_Float16)f.w};
            *(f16x4*)(&Bt[k >> 4][(k >> 3) & 1][keyl][k & 7]) = hv;
        }
        nred[t] = sq;
        if (t < NKT) {
            float v = 0.f;
            if (kb + t < CAP) v = vals[kb + t];
            vv[t] = v;
        }
    }
    __syncthreads();
    if (t < NKT) {
        const float n = nred[4 * t] + nred[4 * t + 1] + nred[4 * t + 2] + nred[4 * t + 3];
        n2c[t] = (kb + t < CAP) ? n * 0.5f : 1e30f;
    }
    __syncthreads();

    const float C1 = 2.0f * LOG2E;
    union U { f32x16 v; f32x4 q[4]; float f[16]; };

#pragma unroll 1
    for (int rg = 0; rg < 8; ++rg) {
        const int rowbase = rg * 128 + wave * 32;
        const _Float16* ap = A + (size_t)(rowbase + n32) * HID + g * 8;

        // acc init = -|k|^2/2 per owned key -> logit = C1 * acc_final
        U acc0, acc1;
#pragma unroll
        for (int rq = 0; rq < 4; ++rq) {
            f32x4 a = *(const f32x4*)&n2c[rq * 8 + g * 4];
            f32x4 b = *(const f32x4*)&n2c[32 + rq * 8 + g * 4];
            acc0.q[rq] = -a;
            acc1.q[rq] = -b;
        }

#pragma unroll
        for (int ks = 0; ks < 16; ++ks) {
            f16x8 bf  = *(const f16x8*)(ap + ks * 16);
            f16x8 kf0 = *(const f16x8*)(&Bt[ks][g][n32][0]);
            f16x8 kf1 = *(const f16x8*)(&Bt[ks][g][32 + n32][0]);
            acc0.v = __builtin_amdgcn_mfma_f32_32x32x16_f16(kf0, bf, acc0.v, 0, 0, 0);
            acc1.v = __builtin_amdgcn_mfma_f32_32x32x16_f16(kf1, bf, acc1.v, 0, 0, 0);
        }

        // ---- in-register softmax partials over the 64-key tile ----
        float m = -3e38f;
#pragma unroll
        for (int r = 0; r < 16; ++r)
            m = fmaxf(m, fmaxf(acc0.f[r], acc1.f[r]));
        m = fmaxf(m, __shfl_xor(m, 32, 64));   // single cross-lane stage
        const float mc = m * C1;               // logits = acc*C1; exp2(acc*C1 - mc)

        float lsum = 0.f, asum = 0.f;
#pragma unroll
        for (int r = 0; r < 16; ++r) {
            const int key0 = (r & 3) + 8 * (r >> 2) + 4 * g;
            const float w0 = exp2f(fmaf(acc0.f[r], C1, -mc));
            const float w1 = exp2f(fmaf(acc1.f[r], C1, -mc));
            lsum += w0 + w1;
            asum = fmaf(w0, vv[key0], fmaf(w1, vv[32 + key0], asum));
        }
        lsum += __shfl_xor(lsum, 32, 64);       // single cross-lane stage
        asum += __shfl_xor(asum, 32, 64);

        if (lane < 32) {
            const int row = rowbase + n32;
            const size_t idx = (size_t)chunk * BATCH + row;
            pm[idx] = mc; pl[idx] = lsum; pa[idx] = asum;
        }
    }
}

// ------------- merge stage 1: 16 chunk-groups x 16 row-blocks -------------
__global__ __launch_bounds__(256) void np_merge1(const float* __restrict__ pm,
                                                 const float* __restrict__ pl,
                                                 const float* __restrict__ pa,
                                                 float* __restrict__ pm2,
                                                 float* __restrict__ pl2,
                                                 float* __restrict__ pa2) {
    const int rb = blockIdx.x & 15;
    const int cgB = blockIdx.x >> 4;
    const int t = threadIdx.x;
    const int row = rb * 64 + (t & 63);
    const int cg = t >> 6;
    const int cend = min((cgB + 1) * CPG, NCHUNK);
    float M = -3e38f, L = 0.f, Acc = 0.f;
    for (int c = cgB * CPG + cg; c < cend; c += 4) {
        const size_t idx = (size_t)c * BATCH + row;
        const float m = pm[idx], l = pl[idx], a = pa[idx];
        const float Mn = fmaxf(M, m);
        const float s0 = exp2f(M - Mn);
        const float s1 = exp2f(m - Mn);
        L = fmaf(L, s0, l * s1);
        Acc = fmaf(Acc, s0, a * s1);
        M = Mn;
    }
    __shared__ float sm[256], sl[256], sa[256];
    sm[t] = M; sl[t] = L; sa[t] = Acc;
    __syncthreads();
    if (t < 64) {
        const float M0 = sm[t], M1 = sm[t + 64], M2 = sm[t + 128], M3 = sm[t + 192];
        const float Mf = fmaxf(fmaxf(M0, M1), fmaxf(M2, M3));
        const float e0 = exp2f(M0 - Mf), e1 = exp2f(M1 - Mf), e2 = exp2f(M2 - Mf), e3 = exp2f(M3 - Mf);
        const float Lf = sl[t] * e0 + sl[t + 64] * e1 + sl[t + 128] * e2 + sl[t + 192] * e3;
        const float Af = sa[t] * e0 + sa[t + 64] * e1 + sa[t + 128] * e2 + sa[t + 192] * e3;
        const size_t o = (size_t)cgB * BATCH + rb * 64 + t;
        pm2[o] = Mf; pl2[o] = Lf; pa2[o] = Af;
    }
}

// ------------- merge stage 2: final 16-way merge, write q1==q2 -------------
__global__ __launch_bounds__(256) void np_merge2(const float* __restrict__ pm2,
                                                 const float* __restrict__ pl2,
                                                 const float* __restrict__ pa2,
                                                 float* __restrict__ out) {
    const int row = blockIdx.x * 256 + threadIdx.x;
    float M = -3e38f, L = 0.f, Acc = 0.f;
#pragma unroll 1
    for (int g = 0; g < CGRP; ++g) {
        const size_t idx = (size_t)g * BATCH + row;
        const float m = pm2[idx], l = pl2[idx], a = pa2[idx];
        const float Mn = fmaxf(M, m);
        const float s0 = exp2f(M - Mn);
        const float s1 = exp2f(m - Mn);
        L = fmaf(L, s0, l * s1);
        Acc = fmaf(Acc, s0, a * s1);
        M = Mn;
    }
    const float qv = Acc / L;
    out[row] = qv;
    out[BATCH + row] = qv;
}

extern "C" void kernel_launch(void* const* d_in, const int* in_sizes, int n_in,
                              void* d_out, int out_size, void* d_ws, size_t ws_size,
                              hipStream_t stream) {
    const float* obs   = (const float*)d_in[0];
    const float* act   = (const float*)d_in[1];
    const float* W     = (const float*)d_in[2];
    const float* bias  = (const float*)d_in[3];
    const float* gamma = (const float*)d_in[4];
    const float* beta  = (const float*)d_in[5];
    const float* keys  = (const float*)d_in[6];
    const float* vals  = (const float*)d_in[7];
    float* out = (float*)d_out;

    char* w = (char*)d_ws;
    _Float16* A = (_Float16*)w;                       // 512 KB
    float* pm = (float*)(w + (1 << 19));
    float* pl = pm + (size_t)NCHUNK * BATCH;          // 3 x 6.25 MB
    float* pa = pl + (size_t)NCHUNK * BATCH;
    float* pm2 = pa + (size_t)NCHUNK * BATCH;         // 3 x 64 KB
    float* pl2 = pm2 + (size_t)CGRP * BATCH;
    float* pa2 = pl2 + (size_t)CGRP * BATCH;

    np_trunk<<<BATCH, 256, 0, stream>>>(obs, act, W, bias, gamma, beta, A);
    np_gemm<<<NCHUNK, 256, 0, stream>>>(keys, vals, A, pm, pl, pa);
    np_merge1<<<CGRP * 16, 256, 0, stream>>>(pm, pl, pa, pm2, pl2, pa2);
    np_merge2<<<BATCH / 256, 256, 0, stream>>>(pm2, pl2, pa2, out);
}